// Round 1
// baseline (2203.733 us; speedup 1.0000x reference)
//
#include <hip/hip_runtime.h>
#include <math.h>

// Problem constants (from reference)
#define HH   2560   // hidden units
#define ESZ  2048   // excitatory units (first ESZ rows/cols)
#define BB   64     // batch
#define TT   32     // time steps
#define INSZ 128    // input size
constexpr float ALPHA_C = 0.2f;   // dt_x / tau_x = 0.02/0.1

__device__ __forceinline__ float retanh_f(float v) { return tanhf(fmaxf(v, 0.f)); }

// Build Weff = |W_rec| * mask_rec (Dale sign + block connectivity + zero diag)
__global__ __launch_bounds__(256) void build_weff(const float* __restrict__ Wrec,
                                                  float* __restrict__ Weff) {
    unsigned idx = blockIdx.x * 256u + threadIdx.x;   // < HH*HH
    unsigned r = idx / HH;
    unsigned c = idx - r * HH;
    bool cE = c < ESZ;
    int ar = (r < ESZ) ? (int)(r >> 9) : (int)((r - ESZ) >> 7);
    int ac = cE ? (int)(c >> 9) : (int)((c - ESZ) >> 7);
    int d = ar - ac;
    bool conn = cE ? (d >= -1 && d <= 1) : (d == 0);
    if (r == c) conn = false;
    float m = conn ? (cE ? 1.f : -1.f) : 0.f;
    Weff[idx] = fabsf(Wrec[idx]) * m;
}

// Transpose state0 -> stateT[h][b], act0[h][b] = retanh(state0) (signed if raw path)
__global__ __launch_bounds__(256) void init_state(const float* __restrict__ state0,
                                                  float* __restrict__ stateT,
                                                  float* __restrict__ act0, int raw) {
    unsigned idx = blockIdx.x * 256u + threadIdx.x;   // < BB*HH
    unsigned b = idx / HH;
    unsigned h = idx - b * HH;
    float s = state0[idx];
    stateT[h * BB + b] = s;
    float o = retanh_f(s);
    if (raw && h >= ESZ) o = -o;
    act0[h * BB + b] = o;
}

// One RNN step. Block = 1 wave (64 threads, lane = batch index), 4 h-rows per block.
// PRE: W is the premasked Weff. !PRE: W is raw W_rec (fabs on the fly, sign folded
// into signed activations, diagonal subtracted).
template <bool PRE>
__global__ __launch_bounds__(64) void step_kernel(
    const float* __restrict__ W,
    const float* __restrict__ W_in,
    const float* __restrict__ b_rec,
    const float* __restrict__ x_t,     // [BB][INSZ] slice at time t
    const float* __restrict__ actIn,   // [HH][BB]
    float* __restrict__ actOut,        // [HH][BB]
    float* __restrict__ stateT,        // [HH][BB]
    float* __restrict__ out_t)         // [BB][HH] slice of d_out at time t
{
    const int lane = threadIdx.x;      // batch index
    const int h0 = blockIdx.x * 4;
    float acc[4] = {0.f, 0.f, 0.f, 0.f};

    // Block-sparse K ranges for this h-tile (tile never crosses an area boundary)
    const bool rE = h0 < ESZ;
    const int a = rE ? (h0 >> 9) : ((h0 - ESZ) >> 7);
    const int e_lo = (a > 0 ? a - 1 : 0) << 9;
    const int e_hi = ((a < 3 ? a + 1 : 3) + 1) << 9;
    const int i_lo = ESZ + (a << 7);

    const float* Wr0 = W + (size_t)(h0 + 0) * HH;
    const float* Wr1 = W + (size_t)(h0 + 1) * HH;
    const float* Wr2 = W + (size_t)(h0 + 2) * HH;
    const float* Wr3 = W + (size_t)(h0 + 3) * HH;

    for (int pass = 0; pass < 2; pass++) {
        const int klo = pass ? i_lo : e_lo;
        const int khi = pass ? (i_lo + 128) : e_hi;
        for (int k = klo; k < khi; k += 16) {
            float av[16];
#pragma unroll
            for (int i = 0; i < 16; i++) av[i] = actIn[(k + i) * BB + lane];
#pragma unroll
            for (int i = 0; i < 16; i++) {
                float w0 = Wr0[k + i];
                float w1 = Wr1[k + i];
                float w2 = Wr2[k + i];
                float w3 = Wr3[k + i];
                if (!PRE) { w0 = fabsf(w0); w1 = fabsf(w1); w2 = fabsf(w2); w3 = fabsf(w3); }
                acc[0] = fmaf(w0, av[i], acc[0]);
                acc[1] = fmaf(w1, av[i], acc[1]);
                acc[2] = fmaf(w2, av[i], acc[2]);
                acc[3] = fmaf(w3, av[i], acc[3]);
            }
        }
    }

    if (!PRE) {
        // remove diagonal contribution (mask has zero diag)
#pragma unroll
        for (int j = 0; j < 4; j++) {
            int hd = h0 + j;
            acc[j] -= fabsf(W[(size_t)hd * HH + hd]) * actIn[hd * BB + lane];
        }
    }

    // Input contribution: only area-0 rows (E: [0,512), I: [2048,2176)), all 128 cols, +1 mask
    if (h0 < 512 || (h0 >= ESZ && h0 < ESZ + 128)) {
        for (int k = 0; k < INSZ; k += 4) {
            float xv[4];
#pragma unroll
            for (int i = 0; i < 4; i++) xv[i] = fmaxf(x_t[lane * INSZ + k + i], 0.f);
#pragma unroll
            for (int i = 0; i < 4; i++) {
                acc[0] = fmaf(fabsf(W_in[(size_t)(h0 + 0) * INSZ + k + i]), xv[i], acc[0]);
                acc[1] = fmaf(fabsf(W_in[(size_t)(h0 + 1) * INSZ + k + i]), xv[i], acc[1]);
                acc[2] = fmaf(fabsf(W_in[(size_t)(h0 + 2) * INSZ + k + i]), xv[i], acc[2]);
                acc[3] = fmaf(fabsf(W_in[(size_t)(h0 + 3) * INSZ + k + i]), xv[i], acc[3]);
            }
        }
    }

    // Epilogue: leaky integrate, write state, output (= next step's activation)
    float o4[4];
#pragma unroll
    for (int j = 0; j < 4; j++) {
        int h = h0 + j;
        float tot = acc[j] + b_rec[h];
        float s = stateT[h * BB + lane];
        float ns = s * (1.f - ALPHA_C) + ALPHA_C * tot;
        stateT[h * BB + lane] = ns;
        float o = retanh_f(ns);
        o4[j] = o;
        if (!PRE && h >= ESZ) o = -o;   // fold Dale sign into activation for raw path
        actOut[h * BB + lane] = o;
    }
    *(float4*)(out_t + (size_t)lane * HH + h0) = make_float4(o4[0], o4[1], o4[2], o4[3]);
}

extern "C" void kernel_launch(void* const* d_in, const int* in_sizes, int n_in,
                              void* d_out, int out_size, void* d_ws, size_t ws_size,
                              hipStream_t stream) {
    const float* x      = (const float*)d_in[0];   // [TT][BB][INSZ]
    const float* W_in   = (const float*)d_in[1];   // [HH][INSZ]
    const float* W_rec  = (const float*)d_in[2];   // [HH][HH]
    const float* b_rec  = (const float*)d_in[3];   // [HH]
    const float* state0 = (const float*)d_in[4];   // [BB][HH]
    float* out = (float*)d_out;                    // [TT][BB][HH]
    float* ws = (float*)d_ws;

    const size_t needPre = ((size_t)HH * HH + 3u * BB * HH) * sizeof(float);
    const bool pre = ws_size >= needPre;

    float* Weff = ws;
    float* stateT = pre ? (ws + (size_t)HH * HH) : ws;
    float* actA = stateT + (size_t)BB * HH;
    float* actB = actA + (size_t)BB * HH;

    if (pre) build_weff<<<(HH * HH) / 256, 256, 0, stream>>>(W_rec, Weff);
    init_state<<<(BB * HH) / 256, 256, 0, stream>>>(state0, stateT, actA, pre ? 0 : 1);

    for (int t = 0; t < TT; t++) {
        const float* ai = (t & 1) ? actB : actA;
        float* ao       = (t & 1) ? actA : actB;
        const float* xt = x + (size_t)t * BB * INSZ;
        float* ot       = out + (size_t)t * BB * HH;
        if (pre)
            step_kernel<true><<<HH / 4, 64, 0, stream>>>(Weff, W_in, b_rec, xt, ai, ao, stateT, ot);
        else
            step_kernel<false><<<HH / 4, 64, 0, stream>>>(W_rec, W_in, b_rec, xt, ai, ao, stateT, ot);
    }
}

// Round 2
// 1884.014 us; speedup vs baseline: 1.1697x; 1.1697x over previous
//
#include <hip/hip_runtime.h>
#include <math.h>

// Problem constants (from reference)
#define HH   2560   // hidden units
#define ESZ  2048   // excitatory units (first ESZ rows/cols)
#define BB   64     // batch
#define TT   32     // time steps
#define INSZ 128    // input size
constexpr float ALPHA_C = 0.2f;   // dt_x / tau_x = 0.02/0.1

__device__ __forceinline__ float retanh_f(float v) { return tanhf(fmaxf(v, 0.f)); }

// Build Weff = |W_rec| * mask_rec (Dale sign + block connectivity + zero diag)
__global__ __launch_bounds__(256) void build_weff(const float* __restrict__ Wrec,
                                                  float* __restrict__ Weff) {
    unsigned idx = blockIdx.x * 256u + threadIdx.x;   // < HH*HH
    unsigned r = idx / HH;
    unsigned c = idx - r * HH;
    bool cE = c < ESZ;
    int ar = (r < ESZ) ? (int)(r >> 9) : (int)((r - ESZ) >> 7);
    int ac = cE ? (int)(c >> 9) : (int)((c - ESZ) >> 7);
    int d = ar - ac;
    bool conn = cE ? (d >= -1 && d <= 1) : (d == 0);
    if (r == c) conn = false;
    float m = conn ? (cE ? 1.f : -1.f) : 0.f;
    Weff[idx] = fabsf(Wrec[idx]) * m;
}

// Transpose state0 -> stateT[h][b], act0[h][b] = retanh(state0) (signed if raw path)
__global__ __launch_bounds__(256) void init_state(const float* __restrict__ state0,
                                                  float* __restrict__ stateT,
                                                  float* __restrict__ act0, int raw) {
    unsigned idx = blockIdx.x * 256u + threadIdx.x;   // < BB*HH
    unsigned b = idx / HH;
    unsigned h = idx - b * HH;
    float s = state0[idx];
    stateT[h * BB + b] = s;
    float o = retanh_f(s);
    if (raw && h >= ESZ) o = -o;
    act0[h * BB + b] = o;
}

// One RNN step. Block = 512 threads = 8 waves; lane = batch index.
// Block owns 8 h-rows; waves split the K (column) range in strided 16-col
// chunks; cross-wave reduction through LDS; epilogue fused.
// PRE: W is premasked Weff. !PRE: raw W_rec (fabs on the fly, sign folded
// into signed activations, diagonal subtracted in epilogue).
template <bool PRE>
__global__ __launch_bounds__(512) void step_kernel(
    const float* __restrict__ W,
    const float* __restrict__ W_in,
    const float* __restrict__ b_rec,
    const float* __restrict__ x_t,     // [BB][INSZ] slice at time t
    const float* __restrict__ actIn,   // [HH][BB]
    float* __restrict__ actOut,        // [HH][BB]
    float* __restrict__ stateT,        // [HH][BB]
    float* __restrict__ out_t)         // [BB][HH] slice of d_out at time t
{
    const int tid  = threadIdx.x;
    const int lane = tid & 63;         // batch index
    const int wv   = tid >> 6;         // wave id 0..7 (k-split)
    const int h0   = blockIdx.x * 8;   // 8 rows per block (never crosses an area boundary)

    float acc[8] = {0.f, 0.f, 0.f, 0.f, 0.f, 0.f, 0.f, 0.f};

    // Block-sparse K ranges for this h-tile
    const bool rE = h0 < ESZ;
    const int a = rE ? (h0 >> 9) : ((h0 - ESZ) >> 7);
    const int e_lo = (a > 0 ? a - 1 : 0) << 9;
    const int e_hi = ((a < 3 ? a + 1 : 3) + 1) << 9;
    const int i_lo = ESZ + (a << 7);

    // E-columns: strided 16-col chunks across the 8 waves
    for (int k = e_lo + wv * 16; k < e_hi; k += 8 * 16) {
        float av[16];
#pragma unroll
        for (int i = 0; i < 16; i++) av[i] = actIn[(k + i) * BB + lane];
#pragma unroll
        for (int j = 0; j < 8; j++) {
            const float* wr = W + (size_t)(h0 + j) * HH + k;
#pragma unroll
            for (int i = 0; i < 16; i++) {
                float w = wr[i];
                if (!PRE) w = fabsf(w);
                acc[j] = fmaf(w, av[i], acc[j]);
            }
        }
    }
    // I-columns: exactly 128 = 8 waves x 16 cols -> one chunk per wave
    {
        const int k = i_lo + wv * 16;
        float av[16];
#pragma unroll
        for (int i = 0; i < 16; i++) av[i] = actIn[(k + i) * BB + lane];
#pragma unroll
        for (int j = 0; j < 8; j++) {
            const float* wr = W + (size_t)(h0 + j) * HH + k;
#pragma unroll
            for (int i = 0; i < 16; i++) {
                float w = wr[i];
                if (!PRE) w = fabsf(w);
                acc[j] = fmaf(w, av[i], acc[j]);
            }
        }
    }

    // Input contribution: only area-0 rows (E: [0,512), I: [2048,2176)), 128 cols, +1 mask
    if (h0 < 512 || (h0 >= ESZ && h0 < ESZ + 128)) {
        const int k = wv * 16;        // 8 waves x 16 = 128 cols
        float xv[16];
#pragma unroll
        for (int i = 0; i < 16; i++) xv[i] = fmaxf(x_t[lane * INSZ + k + i], 0.f);
#pragma unroll
        for (int j = 0; j < 8; j++) {
            const float* wr = W_in + (size_t)(h0 + j) * INSZ + k;
#pragma unroll
            for (int i = 0; i < 16; i++)
                acc[j] = fmaf(fabsf(wr[i]), xv[i], acc[j]);
        }
    }

    // Cross-wave reduction through LDS
    __shared__ float part[8][8][64];   // [wave][row][lane] -> lane-consecutive, conflict-free
#pragma unroll
    for (int j = 0; j < 8; j++) part[wv][j][lane] = acc[j];
    __syncthreads();

    if (tid < 128) {
        const int l = tid & 63;        // batch
        const int g = tid >> 6;        // row group 0..1 (4 rows each)
        float o4[4];
#pragma unroll
        for (int j2 = 0; j2 < 4; j2++) {
            const int j = g * 4 + j2;
            const int h = h0 + j;
            float s = 0.f;
#pragma unroll
            for (int w8 = 0; w8 < 8; w8++) s += part[w8][j][l];
            if (!PRE)   // remove diagonal contribution (mask has zero diag)
                s -= fabsf(W[(size_t)h * HH + h]) * actIn[h * BB + l];
            const float tot = s + b_rec[h];
            const float st = stateT[h * BB + l];
            const float ns = st * (1.f - ALPHA_C) + ALPHA_C * tot;
            stateT[h * BB + l] = ns;
            float o = retanh_f(ns);
            o4[j2] = o;
            if (!PRE && h >= ESZ) o = -o;   // fold Dale sign into activation for raw path
            actOut[h * BB + l] = o;
        }
        *(float4*)(out_t + (size_t)l * HH + h0 + g * 4) =
            make_float4(o4[0], o4[1], o4[2], o4[3]);
    }
}

extern "C" void kernel_launch(void* const* d_in, const int* in_sizes, int n_in,
                              void* d_out, int out_size, void* d_ws, size_t ws_size,
                              hipStream_t stream) {
    const float* x      = (const float*)d_in[0];   // [TT][BB][INSZ]
    const float* W_in   = (const float*)d_in[1];   // [HH][INSZ]
    const float* W_rec  = (const float*)d_in[2];   // [HH][HH]
    const float* b_rec  = (const float*)d_in[3];   // [HH]
    const float* state0 = (const float*)d_in[4];   // [BB][HH]
    float* out = (float*)d_out;                    // [TT][BB][HH]
    float* ws = (float*)d_ws;

    const size_t needPre = ((size_t)HH * HH + 3u * BB * HH) * sizeof(float);
    const bool pre = ws_size >= needPre;

    float* Weff = ws;
    float* stateT = pre ? (ws + (size_t)HH * HH) : ws;
    float* actA = stateT + (size_t)BB * HH;
    float* actB = actA + (size_t)BB * HH;

    if (pre) build_weff<<<(HH * HH) / 256, 256, 0, stream>>>(W_rec, Weff);
    init_state<<<(BB * HH) / 256, 256, 0, stream>>>(state0, stateT, actA, pre ? 0 : 1);

    for (int t = 0; t < TT; t++) {
        const float* ai = (t & 1) ? actB : actA;
        float* ao       = (t & 1) ? actA : actB;
        const float* xt = x + (size_t)t * BB * INSZ;
        float* ot       = out + (size_t)t * BB * HH;
        if (pre)
            step_kernel<true><<<HH / 8, 512, 0, stream>>>(Weff, W_in, b_rec, xt, ai, ao, stateT, ot);
        else
            step_kernel<false><<<HH / 8, 512, 0, stream>>>(W_rec, W_in, b_rec, xt, ai, ao, stateT, ot);
    }
}

// Round 3
// 1870.862 us; speedup vs baseline: 1.1779x; 1.0070x over previous
//
#include <hip/hip_runtime.h>
#include <math.h>

// Problem constants (from reference)
#define HH   2560   // hidden units
#define ESZ  2048   // excitatory units (first ESZ rows/cols)
#define BB   64     // batch
#define TT   32     // time steps
#define INSZ 128    // input size
#define NBLK 256    // one block per CU -> all co-resident (LDS 105KB forces 1/CU)
#define NTHR 512    // 8 waves
#define LDS_BYTES 104960
constexpr float ALPHA_C = 0.2f;   // dt_x / tau_x = 0.02/0.1

__device__ __forceinline__ float retanh_f(float v) { return tanhf(fmaxf(v, 0.f)); }

// area-row index (0..639) -> global row h. Rows of an area: 512 E rows then 128 I rows,
// ALL with identical sparse column ranges (kron structure).
__device__ __forceinline__ int row_h(int area, int idx) {
    return (idx < 512) ? ((area << 9) + idx) : (ESZ + (area << 7) + (idx - 512));
}

// Device-scope sense-reversing grid barrier. Safe because all NBLK blocks are
// co-resident (1 block/CU, grid == CU count).
__device__ __forceinline__ void gridbar(unsigned* cnt, unsigned* gen) {
    __syncthreads();
    if (threadIdx.x == 0) {
        __threadfence();   // release all prior global writes (agent scope)
        unsigned g = __hip_atomic_load(gen, __ATOMIC_RELAXED, __HIP_MEMORY_SCOPE_AGENT);
        unsigned a = __hip_atomic_fetch_add(cnt, 1u, __ATOMIC_ACQ_REL, __HIP_MEMORY_SCOPE_AGENT);
        if (a == NBLK - 1u) {
            __hip_atomic_store(cnt, 0u, __ATOMIC_RELAXED, __HIP_MEMORY_SCOPE_AGENT);
            __hip_atomic_fetch_add(gen, 1u, __ATOMIC_RELEASE, __HIP_MEMORY_SCOPE_AGENT);
        } else {
            while (__hip_atomic_load(gen, __ATOMIC_ACQUIRE, __HIP_MEMORY_SCOPE_AGENT) == g)
                __builtin_amdgcn_s_sleep(16);
        }
        __threadfence();
    }
    __syncthreads();
}

// Persistent RNN: block = 10 rows of one area; W slice (masked, packed) in LDS;
// state in registers; act double-buffered in global ws (paired layout for dwordx2);
// one grid barrier per step.
__global__ __launch_bounds__(NTHR, 2) void rnn_persistent(
    const float* __restrict__ Wrec,  const float* __restrict__ Win,
    const float* __restrict__ brec,  const float* __restrict__ x,
    const float* __restrict__ state0, float* __restrict__ out,
    float* __restrict__ actA, float* __restrict__ actB,
    unsigned* cnt, unsigned* gen)
{
    extern __shared__ float lds[];
    const int tid  = threadIdx.x;
    const int lane = tid & 63;     // batch index
    const int wv   = tid >> 6;     // wave 0..7 (k-split)
    const int area = blockIdx.x >> 6;
    const int rb   = (blockIdx.x & 63) * 10;   // first area-row index of this block

    const int e_lo  = (area > 0 ? area - 1 : 0) << 9;
    const int e_hi  = ((area < 3 ? area + 1 : 3) + 1) << 9;
    const int n_e   = e_hi - e_lo;            // 1024 or 1536
    const int i_lo  = ESZ + (area << 7);
    const int n_rec = n_e + 128;
    const int n_tot = n_rec + (area == 0 ? INSZ : 0);   // 1152/1280/1664

    float* ldsW = lds;                   // [10][n_tot] packed masked weights
    float* part = lds + 10 * n_tot;      // [8][10][64] cross-wave partials
    float* xT   = part + 8 * 10 * 64;    // [128][65] relu(x_t) transposed (area0 only)

    // ---- Stage W slice into LDS (once): |W| * mask, sign folded, diag zeroed,
    //      W_in columns appended for area-0 rows ----
    for (int j = 0; j < 10; j++) {
        const int h = row_h(area, rb + j);
        const float* wr = Wrec + (size_t)h * HH;
        for (int p = tid; p < n_tot; p += NTHR) {
            float w;
            if (p < n_e) {
                int c = e_lo + p;
                w = (c == h) ? 0.f : fabsf(wr[c]);          // E col: +|w|
            } else if (p < n_rec) {
                int c = i_lo + (p - n_e);
                w = (c == h) ? 0.f : -fabsf(wr[c]);         // I col: -|w|
            } else {
                w = fabsf(Win[(size_t)h * INSZ + (p - n_rec)]);  // input col (area0, +1 mask)
            }
            ldsW[j * n_tot + p] = w;
        }
    }

    // ---- Init: state in registers, act0 = retanh(state0) to paired global buffer ----
    float st0, st1 = 0.f;
    {
        int j = tid >> 6;                       // 0..7
        int h = row_h(area, rb + j);
        st0 = state0[(size_t)lane * HH + h];
        actA[((h >> 1) << 7) + lane * 2 + (h & 1)] = retanh_f(st0);
        if (tid < 128) {
            int j2 = 8 + (tid >> 6);            // 8..9
            int h2 = row_h(area, rb + j2);
            st1 = state0[(size_t)lane * HH + h2];
            actA[((h2 >> 1) << 7) + lane * 2 + (h2 & 1)] = retanh_f(st1);
        }
    }

    const int pbeg = wv * (n_tot >> 3);
    const int pend = pbeg + (n_tot >> 3);       // 144/160/208 cols per wave, /16 exact

    gridbar(cnt, gen);   // act0 visible everywhere

    for (int t = 0; t < TT; t++) {
        const float* actIn = (t & 1) ? actB : actA;
        float* actOut      = (t & 1) ? actA : actB;
        const float* xt = x + (size_t)t * BB * INSZ;
        float* out_t    = out + (size_t)t * BB * HH;

        // stage relu(x_t) transposed into LDS (area-0 blocks only)
        if (area == 0) {
            for (int idx = tid; idx < BB * INSZ; idx += NTHR) {
                int b = idx >> 7, k = idx & 127;
                xT[k * 65 + b] = fmaxf(xt[idx], 0.f);
            }
        }
        __syncthreads();

        float2 acc[10];
#pragma unroll
        for (int j = 0; j < 10; j++) acc[j] = make_float2(0.f, 0.f);

        for (int p0 = pbeg; p0 < pend; p0 += 16) {
            float2 av[8];
            if (p0 < n_e) {
                const float* ap = actIn + ((size_t)((e_lo + p0) >> 1)) * 128 + lane * 2;
#pragma unroll
                for (int i = 0; i < 8; i++) av[i] = *(const float2*)(ap + i * 128);
            } else if (p0 < n_rec) {
                const float* ap = actIn + ((size_t)((i_lo + (p0 - n_e)) >> 1)) * 128 + lane * 2;
#pragma unroll
                for (int i = 0; i < 8; i++) av[i] = *(const float2*)(ap + i * 128);
            } else {
                int k0 = p0 - n_rec;
#pragma unroll
                for (int i = 0; i < 8; i++) {
                    av[i].x = xT[(k0 + 2 * i) * 65 + lane];
                    av[i].y = xT[(k0 + 2 * i + 1) * 65 + lane];
                }
            }
#pragma unroll
            for (int j = 0; j < 10; j++) {
                const float* wr = ldsW + j * n_tot + p0;   // wave-uniform -> ds broadcast
#pragma unroll
                for (int i = 0; i < 4; i++) {
                    float4 w4 = *(const float4*)(wr + 4 * i);
                    acc[j].x = fmaf(w4.x, av[2 * i].x,     acc[j].x);
                    acc[j].y = fmaf(w4.y, av[2 * i].y,     acc[j].y);
                    acc[j].x = fmaf(w4.z, av[2 * i + 1].x, acc[j].x);
                    acc[j].y = fmaf(w4.w, av[2 * i + 1].y, acc[j].y);
                }
            }
        }

#pragma unroll
        for (int j = 0; j < 10; j++)
            part[wv * 640 + j * 64 + lane] = acc[j].x + acc[j].y;
        __syncthreads();

        // ---- Epilogue: 640 (row,batch) items over 512 threads; state in registers ----
        {
            int j = tid >> 6;
            int h = row_h(area, rb + j);
            float s = 0.f;
#pragma unroll
            for (int w8 = 0; w8 < 8; w8++) s += part[w8 * 640 + j * 64 + lane];
            float ns = st0 * (1.f - ALPHA_C) + ALPHA_C * (s + brec[h]);
            st0 = ns;
            float o = retanh_f(ns);
            out_t[(size_t)lane * HH + h] = o;
            actOut[((h >> 1) << 7) + lane * 2 + (h & 1)] = o;
            if (tid < 128) {
                int j2 = 8 + (tid >> 6);
                int h2 = row_h(area, rb + j2);
                float s2 = 0.f;
#pragma unroll
                for (int w8 = 0; w8 < 8; w8++) s2 += part[w8 * 640 + j2 * 64 + lane];
                float ns2 = st1 * (1.f - ALPHA_C) + ALPHA_C * (s2 + brec[h2]);
                st1 = ns2;
                float o2 = retanh_f(ns2);
                out_t[(size_t)lane * HH + h2] = o2;
                actOut[((h2 >> 1) << 7) + lane * 2 + (h2 & 1)] = o2;
            }
        }
        gridbar(cnt, gen);   // actOut visible to all blocks before next step
    }
}

extern "C" void kernel_launch(void* const* d_in, const int* in_sizes, int n_in,
                              void* d_out, int out_size, void* d_ws, size_t ws_size,
                              hipStream_t stream) {
    const float* x      = (const float*)d_in[0];   // [TT][BB][INSZ]
    const float* W_in   = (const float*)d_in[1];   // [HH][INSZ]
    const float* W_rec  = (const float*)d_in[2];   // [HH][HH]
    const float* b_rec  = (const float*)d_in[3];   // [HH]
    const float* state0 = (const float*)d_in[4];   // [BB][HH]
    float* out = (float*)d_out;                    // [TT][BB][HH]
    unsigned char* ws = (unsigned char*)d_ws;

    unsigned* cnt = (unsigned*)ws;                 // barrier counter
    unsigned* gen = (unsigned*)(ws + 128);         // barrier generation (separate line)
    float* actA = (float*)(ws + 512);              // paired act layout, [HH/2][BB][2]
    float* actB = actA + (size_t)HH * BB;

    hipMemsetAsync(ws, 0, 256, stream);            // zero barrier state (ws is re-poisoned)
    hipFuncSetAttribute((const void*)rnn_persistent,
                        hipFuncAttributeMaxDynamicSharedMemorySize, LDS_BYTES);
    rnn_persistent<<<NBLK, NTHR, LDS_BYTES, stream>>>(
        W_rec, W_in, b_rec, x, state0, out, actA, actB, cnt, gen);
}

// Round 4
// 1361.483 us; speedup vs baseline: 1.6186x; 1.3741x over previous
//
#include <hip/hip_runtime.h>
#include <math.h>

// Problem constants (from reference)
#define HH    2560   // hidden units
#define ESZ   2048   // excitatory units (first ESZ rows/cols)
#define BB    64     // batch
#define TT    32     // time steps
#define INSZ  128    // input size
#define PITCH 1664   // packed-W pitch in floats (max per-row sparse col count)
#define NROW  10     // rows per block (area-row space; 640 rows/area / 10 = 64 blocks/area)
#define NTHR  1024   // 16 waves per block
#define NBLK  256    // 4 areas * 64 blocks  ->  exactly 1 block per CU, no tail
constexpr float ALPHA_C = 0.2f;   // dt_x / tau_x = 0.02/0.1

__device__ __forceinline__ float retanh_f(float v) { return tanhf(fmaxf(v, 0.f)); }

// Every row of area `a` (E and I alike) has the identical sparse column set:
// E-cols of areas [a-1..a+1] + I-cols of area a (+ input cols for area 0).
__device__ __forceinline__ void area_params(int area, int& e_lo, int& n_e,
                                            int& i_lo, int& n_rec, int& n_tot) {
    e_lo = (area > 0 ? area - 1 : 0) << 9;
    int e_hi = ((area < 3 ? area + 1 : 3) + 1) << 9;
    n_e = e_hi - e_lo;               // 1024 or 1536
    i_lo = ESZ + (area << 7);
    n_rec = n_e + 128;               // 1152 or 1664
    n_tot = n_rec + (area == 0 ? INSZ : 0);   // 1280 / 1664 / 1664 / 1152
}

// area-row index (0..639; 512 E rows then 128 I rows) -> global row h
__device__ __forceinline__ int row_h(int area, int idx) {
    return (idx < 512) ? ((area << 9) + idx) : (ESZ + (area << 7) + (idx - 512));
}

// global row h -> packed row index r (area-major ordering)
__device__ __forceinline__ int pack_r(int h) {
    return (h < ESZ) ? ((h >> 9) * 640 + (h & 511))
                     : (((h - ESZ) >> 7) * 640 + 512 + ((h - ESZ) & 127));
}

// ---- Pack W once: Wp[r][p] = masked/signed/diag-zeroed |W| in dense sparse layout,
//      with W_in columns appended for area-0 rows. grid (13, 2560), block 128.
__global__ __launch_bounds__(128) void pack_w(const float* __restrict__ Wrec,
                                              const float* __restrict__ Win,
                                              float* __restrict__ Wp) {
    const int p = blockIdx.x * 128 + threadIdx.x;   // < PITCH
    const int r = blockIdx.y;                        // < HH
    const int area = r / 640, idx = r % 640;
    int e_lo, n_e, i_lo, n_rec, n_tot;
    area_params(area, e_lo, n_e, i_lo, n_rec, n_tot);
    const int h = row_h(area, idx);
    float w = 0.f;
    if (p < n_e) {
        int c = e_lo + p;
        w = (c == h) ? 0.f : fabsf(Wrec[(size_t)h * HH + c]);        // E col: +|w|
    } else if (p < n_rec) {
        int c = i_lo + (p - n_e);
        w = (c == h) ? 0.f : -fabsf(Wrec[(size_t)h * HH + c]);       // I col: -|w|
    } else if (p < n_tot) {
        w = fabsf(Win[(size_t)h * INSZ + (p - n_rec)]);              // input col (+1 mask)
    }
    Wp[(size_t)r * PITCH + p] = w;
}

// ---- Init: stateT[r][b] (packed-row order), actA = retanh(state0) in paired layout
__global__ __launch_bounds__(256) void init_state2(const float* __restrict__ state0,
                                                   float* __restrict__ stateT,
                                                   float* __restrict__ act0) {
    int idx = blockIdx.x * 256 + threadIdx.x;   // < BB*HH
    int b = idx / HH, h = idx - b * HH;
    float s = state0[idx];
    stateT[pack_r(h) * BB + b] = s;
    act0[((h >> 1) << 7) + b * 2 + (h & 1)] = retanh_f(s);
}

// ---- One RNN step. Block = 1024 thr = 16 waves, 10 area-rows, 16-way K-split.
// lane = batch. W streamed from global (packed if PRE, raw masked-on-the-fly if not);
// act read in paired layout (dwordx2); cross-wave reduce + epilogue fused.
template <bool PRE>
__global__ __launch_bounds__(NTHR, 4) void step2(
    const float* __restrict__ W,       // Wp (PRE) or raw W_rec (!PRE)
    const float* __restrict__ Win,     // used only if !PRE
    const float* __restrict__ brec,
    const float* __restrict__ x_t,     // [BB][INSZ]
    const float* __restrict__ actIn,   // paired [h/2][BB][2]
    float* __restrict__ actOut,
    float* __restrict__ stateT,        // [r][BB]
    float* __restrict__ out_t)         // [BB][HH]
{
    __shared__ float part[16 * NROW * 64];   // 40 KB
    const int tid = threadIdx.x, lane = tid & 63, wv = tid >> 6;
    const int area = blockIdx.x >> 6;
    const int rb = (blockIdx.x & 63) * NROW;
    int e_lo, n_e, i_lo, n_rec, n_tot;
    area_params(area, e_lo, n_e, i_lo, n_rec, n_tot);
    const int r0 = area * 640 + rb;
    const int C = n_tot >> 4;          // 16-col chunks (72/80/104; boundaries 16-aligned)

    float2 acc[NROW];
#pragma unroll
    for (int j = 0; j < NROW; j++) acc[j] = make_float2(0.f, 0.f);

    for (int c = wv; c < C; c += 16) {
        const int p0 = c << 4;
        float2 av[8];
        int cbase;   // global col of p0 (recurrent chunks), for !PRE addressing
        if (p0 < n_rec) {
            cbase = (p0 < n_e) ? (e_lo + p0) : (i_lo + (p0 - n_e));
            const float* ap = actIn + ((cbase >> 1) << 7) + lane * 2;
#pragma unroll
            for (int i = 0; i < 8; i++) av[i] = *(const float2*)(ap + (i << 7));
        } else {
            cbase = -1;
            const int k0 = p0 - n_rec;
            const float4* xp = (const float4*)(x_t + lane * INSZ + k0);
#pragma unroll
            for (int q = 0; q < 4; q++) {
                float4 v = xp[q];
                av[2 * q]     = make_float2(fmaxf(v.x, 0.f), fmaxf(v.y, 0.f));
                av[2 * q + 1] = make_float2(fmaxf(v.z, 0.f), fmaxf(v.w, 0.f));
            }
        }
#pragma unroll
        for (int j = 0; j < NROW; j++) {
            if (PRE) {
                const float4* wp = (const float4*)(W + (size_t)(r0 + j) * PITCH + p0);
#pragma unroll
                for (int q = 0; q < 4; q++) {
                    float4 w = wp[q];
                    acc[j].x = fmaf(w.x, av[2 * q].x,     acc[j].x);
                    acc[j].y = fmaf(w.y, av[2 * q].y,     acc[j].y);
                    acc[j].x = fmaf(w.z, av[2 * q + 1].x, acc[j].x);
                    acc[j].y = fmaf(w.w, av[2 * q + 1].y, acc[j].y);
                }
            } else {
                const int h = row_h(area, rb + j);
                const float sgn = (cbase >= 0 && p0 >= n_e) ? -1.f : 1.f;
                const float* wr = (cbase >= 0) ? (W + (size_t)h * HH + cbase)
                                               : (Win + (size_t)h * INSZ + (p0 - n_rec));
#pragma unroll
                for (int i = 0; i < 8; i++) {
                    float wx = sgn * fabsf(wr[2 * i]);
                    float wy = sgn * fabsf(wr[2 * i + 1]);
                    acc[j].x = fmaf(wx, av[i].x, acc[j].x);
                    acc[j].y = fmaf(wy, av[i].y, acc[j].y);
                }
            }
        }
    }

#pragma unroll
    for (int j = 0; j < NROW; j++)
        part[wv * (NROW * 64) + j * 64 + lane] = acc[j].x + acc[j].y;
    __syncthreads();

    // Epilogue: 640 (row,batch) items. Mapping keeps out writes h-consecutive
    // per 8 lanes (32B granules) for coalescing.
    int j = -1, b = 0;
    if (tid < 512)      { b = tid >> 3;        j = tid & 7; }
    else if (tid < 640) { int u = tid - 512;   b = u >> 1;  j = 8 + (u & 1); }
    if (j >= 0) {
        const int h = row_h(area, rb + j);
        float s = 0.f;
#pragma unroll
        for (int w16 = 0; w16 < 16; w16++) s += part[w16 * (NROW * 64) + j * 64 + b];
        if (!PRE) {   // diag was included above; subtract it (mask has zero diag)
            float sgn = (h < ESZ) ? 1.f : -1.f;
            float ah = actIn[((h >> 1) << 7) + b * 2 + (h & 1)];
            s -= sgn * fabsf(W[(size_t)h * HH + h]) * ah;
        }
        const int r = r0 + j;
        float st = stateT[r * BB + b];
        float ns = st * (1.f - ALPHA_C) + ALPHA_C * (s + brec[h]);
        stateT[r * BB + b] = ns;
        float o = retanh_f(ns);
        out_t[(size_t)b * HH + h] = o;
        actOut[((h >> 1) << 7) + b * 2 + (h & 1)] = o;
    }
}

extern "C" void kernel_launch(void* const* d_in, const int* in_sizes, int n_in,
                              void* d_out, int out_size, void* d_ws, size_t ws_size,
                              hipStream_t stream) {
    const float* x      = (const float*)d_in[0];   // [TT][BB][INSZ]
    const float* W_in   = (const float*)d_in[1];   // [HH][INSZ]
    const float* W_rec  = (const float*)d_in[2];   // [HH][HH]
    const float* b_rec  = (const float*)d_in[3];   // [HH]
    const float* state0 = (const float*)d_in[4];   // [BB][HH]
    float* out = (float*)d_out;                    // [TT][BB][HH]
    float* ws = (float*)d_ws;

    const size_t packElems = (size_t)HH * PITCH;        // 17.0 MB
    const size_t bufElems  = (size_t)HH * BB;           // 0.66 MB
    const bool pre = ws_size >= (packElems + 3 * bufElems) * sizeof(float);

    float* Wp     = ws;
    float* stateT = pre ? (ws + packElems) : ws;
    float* actA   = stateT + bufElems;
    float* actB   = actA + bufElems;

    if (pre) pack_w<<<dim3(13, HH), 128, 0, stream>>>(W_rec, W_in, Wp);
    init_state2<<<(BB * HH) / 256, 256, 0, stream>>>(state0, stateT, actA);

    for (int t = 0; t < TT; t++) {
        const float* ai = (t & 1) ? actB : actA;
        float* ao       = (t & 1) ? actA : actB;
        const float* xt = x + (size_t)t * BB * INSZ;
        float* ot       = out + (size_t)t * BB * HH;
        if (pre)
            step2<true><<<NBLK, NTHR, 0, stream>>>(Wp, W_in, b_rec, xt, ai, ao, stateT, ot);
        else
            step2<false><<<NBLK, NTHR, 0, stream>>>(W_rec, W_in, b_rec, xt, ai, ao, stateT, ot);
    }
}

// Round 5
// 1292.537 us; speedup vs baseline: 1.7050x; 1.0533x over previous
//
#include <hip/hip_runtime.h>
#include <math.h>

// Problem constants (from reference)
#define HH    2560   // hidden units
#define ESZ   2048   // excitatory units (first ESZ rows/cols)
#define BB    64     // batch
#define TT    32     // time steps
#define INSZ  128    // input size
#define PITCH 1664   // packed-W pitch in floats (max per-row sparse col count)
#define NROW  10     // rows per block
#define NTHR  1024   // 16 waves per block
#define NBLK  256    // 4 areas * 64 blocks -> exactly 1 block per CU
#define PJ    68     // part row pitch (floats)  — bank-conflict-free reduce
#define PW    680    // part wave pitch (floats) — 16*680*4B = 43.5 KB
constexpr float ALPHA_C = 0.2f;   // dt_x / tau_x = 0.02/0.1

__device__ __forceinline__ float retanh_f(float v) { return tanhf(fmaxf(v, 0.f)); }

// Every row of area `a` (E and I alike) has the identical sparse column set:
// E-cols of areas [a-1..a+1] + I-cols of area a (+ input cols for area 0).
__device__ __forceinline__ void area_params(int area, int& e_lo, int& n_e,
                                            int& i_lo, int& n_rec, int& n_tot) {
    e_lo = (area > 0 ? area - 1 : 0) << 9;
    int e_hi = ((area < 3 ? area + 1 : 3) + 1) << 9;
    n_e = e_hi - e_lo;               // 1024 or 1536
    i_lo = ESZ + (area << 7);
    n_rec = n_e + 128;               // 1152 or 1664
    n_tot = n_rec + (area == 0 ? INSZ : 0);   // 1280 / 1664 / 1664 / 1152
}

// area-row index (0..639; 512 E rows then 128 I rows) -> global row h
__device__ __forceinline__ int row_h(int area, int idx) {
    return (idx < 512) ? ((area << 9) + idx) : (ESZ + (area << 7) + (idx - 512));
}

// global row h -> packed row index r (area-major ordering)
__device__ __forceinline__ int pack_r(int h) {
    return (h < ESZ) ? ((h >> 9) * 640 + (h & 511))
                     : (((h - ESZ) >> 7) * 640 + 512 + ((h - ESZ) & 127));
}

// ---- Pack W once: Wp[r][p] = masked/signed/diag-zeroed |W| in dense sparse layout,
//      with W_in columns appended for area-0 rows. grid (13, 2560), block 128.
__global__ __launch_bounds__(128) void pack_w(const float* __restrict__ Wrec,
                                              const float* __restrict__ Win,
                                              float* __restrict__ Wp) {
    const int p = blockIdx.x * 128 + threadIdx.x;   // < PITCH
    const int r = blockIdx.y;                        // < HH
    const int area = r / 640, idx = r % 640;
    int e_lo, n_e, i_lo, n_rec, n_tot;
    area_params(area, e_lo, n_e, i_lo, n_rec, n_tot);
    const int h = row_h(area, idx);
    float w = 0.f;
    if (p < n_e) {
        int c = e_lo + p;
        w = (c == h) ? 0.f : fabsf(Wrec[(size_t)h * HH + c]);        // E col: +|w|
    } else if (p < n_rec) {
        int c = i_lo + (p - n_e);
        w = (c == h) ? 0.f : -fabsf(Wrec[(size_t)h * HH + c]);       // I col: -|w|
    } else if (p < n_tot) {
        w = fabsf(Win[(size_t)h * INSZ + (p - n_rec)]);              // input col (+1 mask)
    }
    Wp[(size_t)r * PITCH + p] = w;
}

// ---- Init: stateT[r][b] (packed-row order), actA = retanh(state0) in paired layout
__global__ __launch_bounds__(256) void init_state2(const float* __restrict__ state0,
                                                   float* __restrict__ stateT,
                                                   float* __restrict__ act0) {
    int idx = blockIdx.x * 256 + threadIdx.x;   // < BB*HH
    int b = idx / HH, h = idx - b * HH;
    float s = state0[idx];
    stateT[pack_r(h) * BB + b] = s;
    act0[((h >> 1) << 7) + b * 2 + (h & 1)] = retanh_f(s);
}

// ---- One RNN step, packed-W path. Register-double-buffered W (4-col subchunks).
__global__ __launch_bounds__(NTHR, 4) void step3(
    const float* __restrict__ Wp,      // packed [HH][PITCH]
    const float* __restrict__ brec,
    const float* __restrict__ x_t,     // [BB][INSZ]
    const float* __restrict__ actIn,   // paired [h/2][BB][2]
    float* __restrict__ actOut,
    float* __restrict__ stateT,        // [r][BB]
    float* __restrict__ out_t)         // [BB][HH]
{
    __shared__ float part[16 * PW];    // 43.5 KB, padded pitches
    const int tid = threadIdx.x, lane = tid & 63, wv = tid >> 6;
    // XCD swizzle: consecutive blockIdx round-robin XCDs (bid%8). area=(bid>>1)&3
    // puts each area's 64 blocks on 2 dedicated XCDs -> per-XCD L2 working set =
    // 32 W slices (2.1 MB) + that area's act (<=426 KB) < 4 MB.
    const int bid  = blockIdx.x;
    const int area = (bid >> 1) & 3;
    const int rb   = ((bid >> 3) * 2 + (bid & 1)) * NROW;
    int e_lo, n_e, i_lo, n_rec, n_tot;
    area_params(area, e_lo, n_e, i_lo, n_rec, n_tot);
    const int r0 = area * 640 + rb;
    const int C = n_tot >> 4;          // 16-col chunks

    float2 acc[NROW];
#pragma unroll
    for (int j = 0; j < NROW; j++) acc[j] = make_float2(0.f, 0.f);

    for (int c = wv; c < C; c += 16) {
        const int p0 = c << 4;
        float2 av[8];
        if (p0 < n_rec) {
            const int cb = (p0 < n_e) ? (e_lo + p0) : (i_lo + (p0 - n_e));
            const float* ap = actIn + ((cb >> 1) << 7) + (lane << 1);
#pragma unroll
            for (int i = 0; i < 8; i++) av[i] = *(const float2*)(ap + (i << 7));
        } else {
            const int k0 = p0 - n_rec;
            const float4* xp = (const float4*)(x_t + lane * INSZ + k0);
#pragma unroll
            for (int q = 0; q < 4; q++) {
                float4 v = xp[q];
                av[2 * q]     = make_float2(fmaxf(v.x, 0.f), fmaxf(v.y, 0.f));
                av[2 * q + 1] = make_float2(fmaxf(v.z, 0.f), fmaxf(v.w, 0.f));
            }
        }
        const float* wbase = Wp + (size_t)r0 * PITCH + p0;
        // 4-col subchunks, 2-deep register double buffer: sub s+1's 10 dwordx4
        // loads are in flight while sub s's 40 FMAs execute.
        float4 wbuf0[NROW], wbuf1[NROW];
#pragma unroll
        for (int j = 0; j < NROW; j++)
            wbuf0[j] = *(const float4*)(wbase + j * PITCH);
#pragma unroll
        for (int s = 0; s < 4; s++) {
            float4* wcur = (s & 1) ? wbuf1 : wbuf0;
            float4* wnxt = (s & 1) ? wbuf0 : wbuf1;
            if (s < 3) {
#pragma unroll
                for (int j = 0; j < NROW; j++)
                    wnxt[j] = *(const float4*)(wbase + j * PITCH + (s + 1) * 4);
            }
#pragma unroll
            for (int j = 0; j < NROW; j++) {
                const float4 w = wcur[j];
                acc[j].x = fmaf(w.x, av[2 * s].x,     acc[j].x);
                acc[j].y = fmaf(w.y, av[2 * s].y,     acc[j].y);
                acc[j].x = fmaf(w.z, av[2 * s + 1].x, acc[j].x);
                acc[j].y = fmaf(w.w, av[2 * s + 1].y, acc[j].y);
            }
        }
    }

#pragma unroll
    for (int j = 0; j < NROW; j++)
        part[wv * PW + j * PJ + lane] = acc[j].x + acc[j].y;
    __syncthreads();

    // Epilogue: 640 (row,batch) items; out writes h-consecutive per 8 lanes.
    // part read addr%32 = (8w + 4j + b)%32 -> <=2-way, conflict-free.
    int j = -1, b = 0;
    if (tid < 512)      { b = tid >> 3;      j = tid & 7; }
    else if (tid < 640) { int u = tid - 512; b = u >> 1;  j = 8 + (u & 1); }
    if (j >= 0) {
        const int h = row_h(area, rb + j);
        float s = 0.f;
#pragma unroll
        for (int w16 = 0; w16 < 16; w16++) s += part[w16 * PW + j * PJ + b];
        const int r = r0 + j;
        float st = stateT[r * BB + b];
        float ns = st * (1.f - ALPHA_C) + ALPHA_C * (s + brec[h]);
        stateT[r * BB + b] = ns;
        float o = retanh_f(ns);
        out_t[(size_t)b * HH + h] = o;
        actOut[((h >> 1) << 7) + b * 2 + (h & 1)] = o;
    }
}

// ---- Fallback (no workspace): R3-style streaming of raw W, masked on the fly.
__global__ __launch_bounds__(NTHR, 4) void step_raw(
    const float* __restrict__ W, const float* __restrict__ Win,
    const float* __restrict__ brec, const float* __restrict__ x_t,
    const float* __restrict__ actIn, float* __restrict__ actOut,
    float* __restrict__ stateT, float* __restrict__ out_t)
{
    __shared__ float part[16 * PW];
    const int tid = threadIdx.x, lane = tid & 63, wv = tid >> 6;
    const int area = blockIdx.x >> 6;
    const int rb = (blockIdx.x & 63) * NROW;
    int e_lo, n_e, i_lo, n_rec, n_tot;
    area_params(area, e_lo, n_e, i_lo, n_rec, n_tot);
    const int r0 = area * 640 + rb;
    const int C = n_tot >> 4;

    float2 acc[NROW];
#pragma unroll
    for (int j = 0; j < NROW; j++) acc[j] = make_float2(0.f, 0.f);

    for (int c = wv; c < C; c += 16) {
        const int p0 = c << 4;
        float2 av[8];
        int cbase;
        if (p0 < n_rec) {
            cbase = (p0 < n_e) ? (e_lo + p0) : (i_lo + (p0 - n_e));
            const float* ap = actIn + ((cbase >> 1) << 7) + lane * 2;
#pragma unroll
            for (int i = 0; i < 8; i++) av[i] = *(const float2*)(ap + (i << 7));
        } else {
            cbase = -1;
            const int k0 = p0 - n_rec;
            const float4* xp = (const float4*)(x_t + lane * INSZ + k0);
#pragma unroll
            for (int q = 0; q < 4; q++) {
                float4 v = xp[q];
                av[2 * q]     = make_float2(fmaxf(v.x, 0.f), fmaxf(v.y, 0.f));
                av[2 * q + 1] = make_float2(fmaxf(v.z, 0.f), fmaxf(v.w, 0.f));
            }
        }
#pragma unroll
        for (int j = 0; j < NROW; j++) {
            const int h = row_h(area, rb + j);
            const float sgn = (cbase >= 0 && p0 >= n_e) ? -1.f : 1.f;
            const float* wr = (cbase >= 0) ? (W + (size_t)h * HH + cbase)
                                           : (Win + (size_t)h * INSZ + (p0 - n_rec));
#pragma unroll
            for (int i = 0; i < 8; i++) {
                float wx = sgn * fabsf(wr[2 * i]);
                float wy = sgn * fabsf(wr[2 * i + 1]);
                acc[j].x = fmaf(wx, av[i].x, acc[j].x);
                acc[j].y = fmaf(wy, av[i].y, acc[j].y);
            }
        }
    }

#pragma unroll
    for (int j = 0; j < NROW; j++)
        part[wv * PW + j * PJ + lane] = acc[j].x + acc[j].y;
    __syncthreads();

    int j = -1, b = 0;
    if (tid < 512)      { b = tid >> 3;      j = tid & 7; }
    else if (tid < 640) { int u = tid - 512; b = u >> 1;  j = 8 + (u & 1); }
    if (j >= 0) {
        const int h = row_h(area, rb + j);
        float s = 0.f;
#pragma unroll
        for (int w16 = 0; w16 < 16; w16++) s += part[w16 * PW + j * PJ + b];
        {   // diag was included above; subtract it (mask has zero diag)
            float sgn = (h < ESZ) ? 1.f : -1.f;
            float ah = actIn[((h >> 1) << 7) + b * 2 + (h & 1)];
            s -= sgn * fabsf(W[(size_t)h * HH + h]) * ah;
        }
        const int r = r0 + j;
        float st = stateT[r * BB + b];
        float ns = st * (1.f - ALPHA_C) + ALPHA_C * (s + brec[h]);
        stateT[r * BB + b] = ns;
        float o = retanh_f(ns);
        out_t[(size_t)b * HH + h] = o;
        actOut[((h >> 1) << 7) + b * 2 + (h & 1)] = o;
    }
}

extern "C" void kernel_launch(void* const* d_in, const int* in_sizes, int n_in,
                              void* d_out, int out_size, void* d_ws, size_t ws_size,
                              hipStream_t stream) {
    const float* x      = (const float*)d_in[0];   // [TT][BB][INSZ]
    const float* W_in   = (const float*)d_in[1];   // [HH][INSZ]
    const float* W_rec  = (const float*)d_in[2];   // [HH][HH]
    const float* b_rec  = (const float*)d_in[3];   // [HH]
    const float* state0 = (const float*)d_in[4];   // [BB][HH]
    float* out = (float*)d_out;                    // [TT][BB][HH]
    float* ws = (float*)d_ws;

    const size_t packElems = (size_t)HH * PITCH;
    const size_t bufElems  = (size_t)HH * BB;
    const bool pre = ws_size >= (packElems + 3 * bufElems) * sizeof(float);

    float* Wp     = ws;
    float* stateT = pre ? (ws + packElems) : ws;
    float* actA   = stateT + bufElems;
    float* actB   = actA + bufElems;

    if (pre) pack_w<<<dim3(13, HH), 128, 0, stream>>>(W_rec, W_in, Wp);
    init_state2<<<(BB * HH) / 256, 256, 0, stream>>>(state0, stateT, actA);

    for (int t = 0; t < TT; t++) {
        const float* ai = (t & 1) ? actB : actA;
        float* ao       = (t & 1) ? actA : actB;
        const float* xt = x + (size_t)t * BB * INSZ;
        float* ot       = out + (size_t)t * BB * HH;
        if (pre)
            step3<<<NBLK, NTHR, 0, stream>>>(Wp, b_rec, xt, ai, ao, stateT, ot);
        else
            step_raw<<<NBLK, NTHR, 0, stream>>>(W_rec, W_in, b_rec, xt, ai, ao, stateT, ot);
    }
}

// Round 6
// 544.961 us; speedup vs baseline: 4.0438x; 2.3718x over previous
//
#include <hip/hip_runtime.h>
#include <math.h>

// Problem constants (from reference)
#define HH    2560   // hidden units
#define ESZ   2048   // excitatory units (first ESZ rows/cols)
#define BB    64     // batch
#define TT    32     // time steps
#define INSZ  128    // input size
#define PITCH 1664   // packed-W pitch in floats; row stride bytes = 6656
#define NROW  10     // rows per block
#define NTHR  1024   // 16 waves per block
#define NBLK  256    // exactly 1 block per CU (LDS-forced)
#define PJ    68     // part row pitch (floats)  — conflict-free reduce
#define PW    680    // part wave pitch (floats)
constexpr float ALPHA_C = 0.2f;   // dt_x / tau_x = 0.02/0.1

typedef __attribute__((ext_vector_type(4))) float sf4;   // SGPR quad for s_load_dwordx4

__device__ __forceinline__ float retanh_f(float v) { return tanhf(fmaxf(v, 0.f)); }

// Every row of area `a` (E and I alike) has the identical sparse column set:
// E-cols of areas [a-1..a+1] + I-cols of area a (+ input cols for area 0).
__device__ __forceinline__ void area_params(int area, int& e_lo, int& n_e,
                                            int& i_lo, int& n_rec, int& n_tot) {
    e_lo = (area > 0 ? area - 1 : 0) << 9;
    int e_hi = ((area < 3 ? area + 1 : 3) + 1) << 9;
    n_e = e_hi - e_lo;               // 1024 or 1536
    i_lo = ESZ + (area << 7);
    n_rec = n_e + 128;               // 1152 or 1664
    n_tot = n_rec + (area == 0 ? INSZ : 0);   // 1280 / 1664 / 1664 / 1152
}

// area-row index (0..639; 512 E rows then 128 I rows) -> global row h
__device__ __forceinline__ int row_h(int area, int idx) {
    return (idx < 512) ? ((area << 9) + idx) : (ESZ + (area << 7) + (idx - 512));
}

// global row h -> packed row index r (area-major ordering)
__device__ __forceinline__ int pack_r(int h) {
    return (h < ESZ) ? ((h >> 9) * 640 + (h & 511))
                     : (((h - ESZ) >> 7) * 640 + 512 + ((h - ESZ) & 127));
}

// ---- Pack W once: Wp[r][p] = masked/signed/diag-zeroed |W| in dense sparse layout,
//      with W_in columns appended for area-0 rows. grid (13, 2560), block 128.
__global__ __launch_bounds__(128) void pack_w(const float* __restrict__ Wrec,
                                              const float* __restrict__ Win,
                                              float* __restrict__ Wp) {
    const int p = blockIdx.x * 128 + threadIdx.x;   // < PITCH
    const int r = blockIdx.y;                        // < HH
    const int area = r / 640, idx = r % 640;
    int e_lo, n_e, i_lo, n_rec, n_tot;
    area_params(area, e_lo, n_e, i_lo, n_rec, n_tot);
    const int h = row_h(area, idx);
    float w = 0.f;
    if (p < n_e) {
        int c = e_lo + p;
        w = (c == h) ? 0.f : fabsf(Wrec[(size_t)h * HH + c]);        // E col: +|w|
    } else if (p < n_rec) {
        int c = i_lo + (p - n_e);
        w = (c == h) ? 0.f : -fabsf(Wrec[(size_t)h * HH + c]);       // I col: -|w|
    } else if (p < n_tot) {
        w = fabsf(Win[(size_t)h * INSZ + (p - n_rec)]);              // input col (+1 mask)
    }
    Wp[(size_t)r * PITCH + p] = w;
}

// ---- Init: stateT[r][b] (packed-row order), actA = retanh(state0) in paired layout
__global__ __launch_bounds__(256) void init_state2(const float* __restrict__ state0,
                                                   float* __restrict__ stateT,
                                                   float* __restrict__ act0) {
    int idx = blockIdx.x * 256 + threadIdx.x;   // < BB*HH
    int b = idx / HH, h = idx - b * HH;
    float s = state0[idx];
    stateT[pack_r(h) * BB + b] = s;
    act0[((h >> 1) << 7) + b * 2 + (h & 1)] = retanh_f(s);
}

// ---- One RNN step, packed-W path. W via SCALAR loads (s_load_dwordx4, inline asm):
// wave-uniform W rows ride the scalar pipe into SGPRs; the vector pipe carries only
// act loads (prefetched one chunk ahead); VALU does v_fmac_f32 with 1 SGPR operand.
__global__ __launch_bounds__(NTHR, 4) void step4(
    const float* __restrict__ Wp,      // packed [HH][PITCH]
    const float* __restrict__ brec,
    const float* __restrict__ x_t,     // [BB][INSZ]
    const float* __restrict__ actIn,   // paired [h/2][BB][2]
    float* __restrict__ actOut,
    float* __restrict__ stateT,        // [r][BB]
    float* __restrict__ out_t)         // [BB][HH]
{
    // 84000 B static LDS: only 1 block/CU can fit -> even 1-block-per-CU spread.
    __shared__ float part[21000];
    const int tid = threadIdx.x, lane = tid & 63, wv = tid >> 6;
    // XCD swizzle: bid%8 = XCD; area=(bid>>1)&3 pins each area to 2 XCDs.
    const int bid  = blockIdx.x;
    const int area = (bid >> 1) & 3;
    const int rb   = ((bid >> 3) * 2 + (bid & 1)) * NROW;
    int e_lo, n_e, i_lo, n_rec, n_tot;
    area_params(area, e_lo, n_e, i_lo, n_rec, n_tot);
    const int r0 = area * 640 + rb;
    const int C4 = n_tot >> 2;          // 4-col chunks (288..416), 16-way wave split

    float2 acc[NROW];
#pragma unroll
    for (int j = 0; j < NROW; j++) acc[j] = make_float2(0.f, 0.f);

    // act loader for a 4-col chunk starting at packed col p0 (4-aligned)
    auto load_act = [&](int p0, float2& o0, float2& o1) {
        if (p0 < n_rec) {
            const int cb = (p0 < n_e) ? (e_lo + p0) : (i_lo + (p0 - n_e));
            const float* ap = actIn + ((cb >> 1) << 7) + (lane << 1);
            o0 = *(const float2*)ap;            // cols p0, p0+1 for this batch lane
            o1 = *(const float2*)(ap + 128);    // cols p0+2, p0+3
        } else {
            const int k0 = p0 - n_rec;
            float4 v = *(const float4*)(x_t + lane * INSZ + k0);
            o0 = make_float2(fmaxf(v.x, 0.f), fmaxf(v.y, 0.f));
            o1 = make_float2(fmaxf(v.z, 0.f), fmaxf(v.w, 0.f));
        }
    };

    float2 a0, a1, b0, b1;
    int c = wv;
    if (c < C4) load_act(c << 2, a0, a1);
    while (c < C4) {
        const int cn = c + 16;
        if (cn < C4) load_act(cn << 2, b0, b1);   // prefetch next chunk's act (vmcnt)

        // Uniform W base for this chunk (readfirstlane -> SGPR address)
        const float* wb = Wp + (size_t)r0 * PITCH
                             + ((size_t)__builtin_amdgcn_readfirstlane(c) << 2);
        sf4 w0, w1, w2, w3, w4, w5, w6, w7, w8, w9;
        // Issue 10 scalar loads, one per row (imm offset = j * 6656 bytes)
        asm volatile(
            "s_load_dwordx4 %0, %10, 0x0\n\t"
            "s_load_dwordx4 %1, %10, 0x1a00\n\t"
            "s_load_dwordx4 %2, %10, 0x3400\n\t"
            "s_load_dwordx4 %3, %10, 0x4e00\n\t"
            "s_load_dwordx4 %4, %10, 0x6800\n\t"
            "s_load_dwordx4 %5, %10, 0x8200\n\t"
            "s_load_dwordx4 %6, %10, 0x9c00\n\t"
            "s_load_dwordx4 %7, %10, 0xb600\n\t"
            "s_load_dwordx4 %8, %10, 0xd000\n\t"
            "s_load_dwordx4 %9, %10, 0xea00"
            : "=&s"(w0), "=&s"(w1), "=&s"(w2), "=&s"(w3), "=&s"(w4),
              "=&s"(w5), "=&s"(w6), "=&s"(w7), "=&s"(w8), "=&s"(w9)
            : "s"(wb));
        // Wait for scalar returns; tie values through so uses can't be hoisted above.
        asm volatile("s_waitcnt lgkmcnt(0)"
            : "+s"(w0), "+s"(w1), "+s"(w2), "+s"(w3), "+s"(w4),
              "+s"(w5), "+s"(w6), "+s"(w7), "+s"(w8), "+s"(w9));

#define FMA4(J, W)                                   \
        acc[J].x = fmaf(W.x, a0.x, acc[J].x);        \
        acc[J].y = fmaf(W.y, a0.y, acc[J].y);        \
        acc[J].x = fmaf(W.z, a1.x, acc[J].x);        \
        acc[J].y = fmaf(W.w, a1.y, acc[J].y);
        FMA4(0, w0) FMA4(1, w1) FMA4(2, w2) FMA4(3, w3) FMA4(4, w4)
        FMA4(5, w5) FMA4(6, w6) FMA4(7, w7) FMA4(8, w8) FMA4(9, w9)
#undef FMA4

        a0 = b0; a1 = b1;
        c = cn;
    }

#pragma unroll
    for (int j = 0; j < NROW; j++)
        part[wv * PW + j * PJ + lane] = acc[j].x + acc[j].y;
    __syncthreads();

    // Epilogue: 640 (row,batch) items; out writes h-consecutive per 8 lanes.
    int j = -1, b = 0;
    if (tid < 512)      { b = tid >> 3;      j = tid & 7; }
    else if (tid < 640) { int u = tid - 512; b = u >> 1;  j = 8 + (u & 1); }
    if (j >= 0) {
        const int h = row_h(area, rb + j);
        float s = 0.f;
#pragma unroll
        for (int w16 = 0; w16 < 16; w16++) s += part[w16 * PW + j * PJ + b];
        const int r = r0 + j;
        float st = stateT[r * BB + b];
        float ns = st * (1.f - ALPHA_C) + ALPHA_C * (s + brec[h]);
        stateT[r * BB + b] = ns;
        float o = retanh_f(ns);
        out_t[(size_t)b * HH + h] = o;
        actOut[((h >> 1) << 7) + b * 2 + (h & 1)] = o;
    }
}

// ---- Fallback (no workspace): stream raw W, masked on the fly (R3-style).
__global__ __launch_bounds__(NTHR, 4) void step_raw(
    const float* __restrict__ W, const float* __restrict__ Win,
    const float* __restrict__ brec, const float* __restrict__ x_t,
    const float* __restrict__ actIn, float* __restrict__ actOut,
    float* __restrict__ stateT, float* __restrict__ out_t)
{
    __shared__ float part[16 * PW];
    const int tid = threadIdx.x, lane = tid & 63, wv = tid >> 6;
    const int area = blockIdx.x >> 6;
    const int rb = (blockIdx.x & 63) * NROW;
    int e_lo, n_e, i_lo, n_rec, n_tot;
    area_params(area, e_lo, n_e, i_lo, n_rec, n_tot);
    const int r0 = area * 640 + rb;
    const int C = n_tot >> 4;

    float2 acc[NROW];
#pragma unroll
    for (int j = 0; j < NROW; j++) acc[j] = make_float2(0.f, 0.f);

    for (int c = wv; c < C; c += 16) {
        const int p0 = c << 4;
        float2 av[8];
        int cbase;
        if (p0 < n_rec) {
            cbase = (p0 < n_e) ? (e_lo + p0) : (i_lo + (p0 - n_e));
            const float* ap = actIn + ((cbase >> 1) << 7) + lane * 2;
#pragma unroll
            for (int i = 0; i < 8; i++) av[i] = *(const float2*)(ap + (i << 7));
        } else {
            cbase = -1;
            const int k0 = p0 - n_rec;
            const float4* xp = (const float4*)(x_t + lane * INSZ + k0);
#pragma unroll
            for (int q = 0; q < 4; q++) {
                float4 v = xp[q];
                av[2 * q]     = make_float2(fmaxf(v.x, 0.f), fmaxf(v.y, 0.f));
                av[2 * q + 1] = make_float2(fmaxf(v.z, 0.f), fmaxf(v.w, 0.f));
            }
        }
#pragma unroll
        for (int j = 0; j < NROW; j++) {
            const int h = row_h(area, rb + j);
            const float sgn = (cbase >= 0 && p0 >= n_e) ? -1.f : 1.f;
            const float* wr = (cbase >= 0) ? (W + (size_t)h * HH + cbase)
                                           : (Win + (size_t)h * INSZ + (p0 - n_rec));
#pragma unroll
            for (int i = 0; i < 8; i++) {
                float wx = sgn * fabsf(wr[2 * i]);
                float wy = sgn * fabsf(wr[2 * i + 1]);
                acc[j].x = fmaf(wx, av[i].x, acc[j].x);
                acc[j].y = fmaf(wy, av[i].y, acc[j].y);
            }
        }
    }

#pragma unroll
    for (int j = 0; j < NROW; j++)
        part[wv * PW + j * PJ + lane] = acc[j].x + acc[j].y;
    __syncthreads();

    int j = -1, b = 0;
    if (tid < 512)      { b = tid >> 3;      j = tid & 7; }
    else if (tid < 640) { int u = tid - 512; b = u >> 1;  j = 8 + (u & 1); }
    if (j >= 0) {
        const int h = row_h(area, rb + j);
        float s = 0.f;
#pragma unroll
        for (int w16 = 0; w16 < 16; w16++) s += part[w16 * PW + j * PJ + b];
        {   // diag was included above; subtract it (mask has zero diag)
            float sgn = (h < ESZ) ? 1.f : -1.f;
            float ah = actIn[((h >> 1) << 7) + b * 2 + (h & 1)];
            s -= sgn * fabsf(W[(size_t)h * HH + h]) * ah;
        }
        const int r = r0 + j;
        float st = stateT[r * BB + b];
        float ns = st * (1.f - ALPHA_C) + ALPHA_C * (s + brec[h]);
        stateT[r * BB + b] = ns;
        float o = retanh_f(ns);
        out_t[(size_t)b * HH + h] = o;
        actOut[((h >> 1) << 7) + b * 2 + (h & 1)] = o;
    }
}

extern "C" void kernel_launch(void* const* d_in, const int* in_sizes, int n_in,
                              void* d_out, int out_size, void* d_ws, size_t ws_size,
                              hipStream_t stream) {
    const float* x      = (const float*)d_in[0];   // [TT][BB][INSZ]
    const float* W_in   = (const float*)d_in[1];   // [HH][INSZ]
    const float* W_rec  = (const float*)d_in[2];   // [HH][HH]
    const float* b_rec  = (const float*)d_in[3];   // [HH]
    const float* state0 = (const float*)d_in[4];   // [BB][HH]
    float* out = (float*)d_out;                    // [TT][BB][HH]
    float* ws = (float*)d_ws;

    const size_t packElems = (size_t)HH * PITCH;
    const size_t bufElems  = (size_t)HH * BB;
    const bool pre = ws_size >= (packElems + 3 * bufElems) * sizeof(float);

    float* Wp     = ws;
    float* stateT = pre ? (ws + packElems) : ws;
    float* actA   = stateT + bufElems;
    float* actB   = actA + bufElems;

    if (pre) pack_w<<<dim3(13, HH), 128, 0, stream>>>(W_rec, W_in, Wp);
    init_state2<<<(BB * HH) / 256, 256, 0, stream>>>(state0, stateT, actA);

    for (int t = 0; t < TT; t++) {
        const float* ai = (t & 1) ? actB : actA;
        float* ao       = (t & 1) ? actA : actB;
        const float* xt = x + (size_t)t * BB * INSZ;
        float* ot       = out + (size_t)t * BB * HH;
        if (pre)
            step4<<<NBLK, NTHR, 0, stream>>>(Wp, b_rec, xt, ai, ao, stateT, ot);
        else
            step_raw<<<NBLK, NTHR, 0, stream>>>(W_rec, W_in, b_rec, xt, ai, ao, stateT, ot);
    }
}

// Round 7
// 530.308 us; speedup vs baseline: 4.1556x; 1.0276x over previous
//
#include <hip/hip_runtime.h>
#include <math.h>

// Problem constants (from reference)
#define HH    2560   // hidden units
#define ESZ   2048   // excitatory units (first ESZ rows/cols)
#define BB    64     // batch
#define TT    32     // time steps
#define INSZ  128    // input size
#define PITCH 1664   // packed-W pitch in floats; row stride bytes = 6656 (0x1a00)
#define NROW  10     // rows per block
#define NTHR  1024   // 16 waves per block
#define NBLK  256    // exactly 1 block per CU (LDS-forced)
#define PJ    68     // part row pitch (floats)  — conflict-free reduce
#define PW    680    // part wave pitch (floats)
constexpr float ALPHA_C = 0.2f;   // dt_x / tau_x = 0.02/0.1

typedef __attribute__((ext_vector_type(4))) float sf4;   // SGPR quad for s_load_dwordx4

__device__ __forceinline__ float retanh_f(float v) { return tanhf(fmaxf(v, 0.f)); }

// Every row of area `a` (E and I alike) has the identical sparse column set:
// E-cols of areas [a-1..a+1] + I-cols of area a (+ input cols for area 0).
__device__ __forceinline__ void area_params(int area, int& e_lo, int& n_e,
                                            int& i_lo, int& n_rec, int& n_tot) {
    e_lo = (area > 0 ? area - 1 : 0) << 9;
    int e_hi = ((area < 3 ? area + 1 : 3) + 1) << 9;
    n_e = e_hi - e_lo;               // 1024 or 1536
    i_lo = ESZ + (area << 7);
    n_rec = n_e + 128;               // 1152 or 1664
    n_tot = n_rec + (area == 0 ? INSZ : 0);   // 1280 / 1664 / 1664 / 1152
}

// area-row index (0..639; 512 E rows then 128 I rows) -> global row h
__device__ __forceinline__ int row_h(int area, int idx) {
    return (idx < 512) ? ((area << 9) + idx) : (ESZ + (area << 7) + (idx - 512));
}

// global row h -> packed row index r (area-major ordering)
__device__ __forceinline__ int pack_r(int h) {
    return (h < ESZ) ? ((h >> 9) * 640 + (h & 511))
                     : (((h - ESZ) >> 7) * 640 + 512 + ((h - ESZ) & 127));
}

// ---- Pack W once: Wp[r][p] = masked/signed/diag-zeroed |W| in dense sparse layout,
//      with W_in columns appended for area-0 rows. grid (13, 2560), block 128.
__global__ __launch_bounds__(128) void pack_w(const float* __restrict__ Wrec,
                                              const float* __restrict__ Win,
                                              float* __restrict__ Wp) {
    const int p = blockIdx.x * 128 + threadIdx.x;   // < PITCH
    const int r = blockIdx.y;                        // < HH
    const int area = r / 640, idx = r % 640;
    int e_lo, n_e, i_lo, n_rec, n_tot;
    area_params(area, e_lo, n_e, i_lo, n_rec, n_tot);
    const int h = row_h(area, idx);
    float w = 0.f;
    if (p < n_e) {
        int c = e_lo + p;
        w = (c == h) ? 0.f : fabsf(Wrec[(size_t)h * HH + c]);        // E col: +|w|
    } else if (p < n_rec) {
        int c = i_lo + (p - n_e);
        w = (c == h) ? 0.f : -fabsf(Wrec[(size_t)h * HH + c]);       // I col: -|w|
    } else if (p < n_tot) {
        w = fabsf(Win[(size_t)h * INSZ + (p - n_rec)]);              // input col (+1 mask)
    }
    Wp[(size_t)r * PITCH + p] = w;
}

// ---- Init: stateT[r][b] (packed-row order), actA = retanh(state0) in paired layout
__global__ __launch_bounds__(256) void init_state2(const float* __restrict__ state0,
                                                   float* __restrict__ stateT,
                                                   float* __restrict__ act0) {
    int idx = blockIdx.x * 256 + threadIdx.x;   // < BB*HH
    int b = idx / HH, h = idx - b * HH;
    float s = state0[idx];
    stateT[pack_r(h) * BB + b] = s;
    act0[((h >> 1) << 7) + b * 2 + (h & 1)] = retanh_f(s);
}

// Issue 10 s_load_dwordx4 at byte offsets j*0x1a00 (prologue, imm base 0)
#define ISSUE0(Q0,Q1,Q2,Q3,Q4,Q5,Q6,Q7,Q8,Q9,BASE)                        \
    asm volatile(                                                          \
        "s_load_dwordx4 %0, %10, 0x0\n\t"                                  \
        "s_load_dwordx4 %1, %10, 0x1a00\n\t"                               \
        "s_load_dwordx4 %2, %10, 0x3400\n\t"                               \
        "s_load_dwordx4 %3, %10, 0x4e00\n\t"                               \
        "s_load_dwordx4 %4, %10, 0x6800\n\t"                               \
        "s_load_dwordx4 %5, %10, 0x8200\n\t"                               \
        "s_load_dwordx4 %6, %10, 0x9c00\n\t"                               \
        "s_load_dwordx4 %7, %10, 0xb600\n\t"                               \
        "s_load_dwordx4 %8, %10, 0xd000\n\t"                               \
        "s_load_dwordx4 %9, %10, 0xea00"                                   \
        : "=&s"(Q0), "=&s"(Q1), "=&s"(Q2), "=&s"(Q3), "=&s"(Q4),           \
          "=&s"(Q5), "=&s"(Q6), "=&s"(Q7), "=&s"(Q8), "=&s"(Q9)            \
        : "s"(BASE))

// Issue 10 s_load_dwordx4 for the NEXT chunk: offsets +0x100 (next chunk is
// 16 chunks * 16 B = 256 B ahead of the current base)
#define ISSUEN(Q0,Q1,Q2,Q3,Q4,Q5,Q6,Q7,Q8,Q9,BASE)                        \
    asm volatile(                                                          \
        "s_load_dwordx4 %0, %10, 0x100\n\t"                                \
        "s_load_dwordx4 %1, %10, 0x1b00\n\t"                               \
        "s_load_dwordx4 %2, %10, 0x3500\n\t"                               \
        "s_load_dwordx4 %3, %10, 0x4f00\n\t"                               \
        "s_load_dwordx4 %4, %10, 0x6900\n\t"                               \
        "s_load_dwordx4 %5, %10, 0x8300\n\t"                               \
        "s_load_dwordx4 %6, %10, 0x9d00\n\t"                               \
        "s_load_dwordx4 %7, %10, 0xb700\n\t"                               \
        "s_load_dwordx4 %8, %10, 0xd100\n\t"                               \
        "s_load_dwordx4 %9, %10, 0xeb00"                                   \
        : "=&s"(Q0), "=&s"(Q1), "=&s"(Q2), "=&s"(Q3), "=&s"(Q4),           \
          "=&s"(Q5), "=&s"(Q6), "=&s"(Q7), "=&s"(Q8), "=&s"(Q9)            \
        : "s"(BASE))

// Drain scalar returns; tie values so uses can't be hoisted above the wait.
#define WAITQ(Q0,Q1,Q2,Q3,Q4,Q5,Q6,Q7,Q8,Q9)                              \
    asm volatile("s_waitcnt lgkmcnt(0)"                                    \
        : "+s"(Q0), "+s"(Q1), "+s"(Q2), "+s"(Q3), "+s"(Q4),                \
          "+s"(Q5), "+s"(Q6), "+s"(Q7), "+s"(Q8), "+s"(Q9))

#define FMA4(J, W, A0, A1)                           \
    acc[J].x = fmaf(W.x, A0.x, acc[J].x);            \
    acc[J].y = fmaf(W.y, A0.y, acc[J].y);            \
    acc[J].x = fmaf(W.z, A1.x, acc[J].x);            \
    acc[J].y = fmaf(W.w, A1.y, acc[J].y);

#define FMA_ALL(Q0,Q1,Q2,Q3,Q4,Q5,Q6,Q7,Q8,Q9,A0,A1)                      \
    FMA4(0,Q0,A0,A1) FMA4(1,Q1,A0,A1) FMA4(2,Q2,A0,A1) FMA4(3,Q3,A0,A1)   \
    FMA4(4,Q4,A0,A1) FMA4(5,Q5,A0,A1) FMA4(6,Q6,A0,A1) FMA4(7,Q7,A0,A1)   \
    FMA4(8,Q8,A0,A1) FMA4(9,Q9,A0,A1)

// ---- One RNN step. W rides the scalar pipe, software-pipelined 2 deep:
// chunk c+1's s_loads are issued BEFORE chunk c's 40 FMAs, and the coarse
// lgkmcnt(0) drain is deferred until after those FMAs -> scalar latency hidden.
__global__ __launch_bounds__(NTHR, 4) void step5(
    const float* __restrict__ Wp,      // packed [HH][PITCH]
    const float* __restrict__ brec,
    const float* __restrict__ x_t,     // [BB][INSZ]
    const float* __restrict__ actIn,   // paired [h/2][BB][2]
    float* __restrict__ actOut,
    float* __restrict__ stateT,        // [r][BB]
    float* __restrict__ out_t)         // [BB][HH]
{
    // 84000 B static LDS: only 1 block/CU can fit -> even 1-block-per-CU spread.
    __shared__ float part[21000];
    const int tid = threadIdx.x, lane = tid & 63, wv = tid >> 6;
    // XCD swizzle: bid%8 = XCD; area=(bid>>1)&3 pins each area to 2 XCDs.
    const int bid  = blockIdx.x;
    const int area = (bid >> 1) & 3;
    const int rb   = ((bid >> 3) * 2 + (bid & 1)) * NROW;
    int e_lo, n_e, i_lo, n_rec, n_tot;
    area_params(area, e_lo, n_e, i_lo, n_rec, n_tot);
    const int r0 = area * 640 + rb;
    const int C4 = n_tot >> 2;          // 4-col chunks; C4 % 16 == 0
    const int phases = C4 >> 4;         // chunks per wave: 18 / 20 / 26 (always even)

    float2 acc[NROW];
#pragma unroll
    for (int j = 0; j < NROW; j++) acc[j] = make_float2(0.f, 0.f);

    // act loader for a 4-col chunk starting at packed col p0 (4-aligned)
    auto load_act = [&](int p0, float2& o0, float2& o1) {
        if (p0 < n_rec) {
            const int cb = (p0 < n_e) ? (e_lo + p0) : (i_lo + (p0 - n_e));
            const float* ap = actIn + ((cb >> 1) << 7) + (lane << 1);
            o0 = *(const float2*)ap;            // cols p0, p0+1 for this batch lane
            o1 = *(const float2*)(ap + 128);    // cols p0+2, p0+3
        } else {
            const int k0 = p0 - n_rec;
            float4 v = *(const float4*)(x_t + lane * INSZ + k0);
            o0 = make_float2(fmaxf(v.x, 0.f), fmaxf(v.y, 0.f));
            o1 = make_float2(fmaxf(v.z, 0.f), fmaxf(v.w, 0.f));
        }
    };

    // Wave-uniform W base for this wave's first chunk; advances 256 B per phase.
    const float* wb = Wp + (size_t)r0 * PITCH
                         + ((size_t)__builtin_amdgcn_readfirstlane(wv) << 2);
    sf4 A0,A1,A2,A3,A4,A5,A6,A7,A8,A9;
    sf4 B0,B1,B2,B3,B4,B5,B6,B7,B8,B9;
    float2 a0, a1, b0, b1;
    int c = wv;

    // Prologue: chunk c into A (exposed latency once), act for c.
    ISSUE0(A0,A1,A2,A3,A4,A5,A6,A7,A8,A9, wb);
    load_act(c << 2, a0, a1);
    WAITQ(A0,A1,A2,A3,A4,A5,A6,A7,A8,A9);

    for (int ph = 0; ph < phases; ph += 2) {
        // ---- phase A: compute chunk c from A; prefetch chunk c+16 into B ----
        const bool pf1 = (ph + 1 < phases);
        if (pf1) {
            ISSUEN(B0,B1,B2,B3,B4,B5,B6,B7,B8,B9, wb);
            load_act((c + 16) << 2, b0, b1);
        }
        FMA_ALL(A0,A1,A2,A3,A4,A5,A6,A7,A8,A9, a0, a1);
        if (!pf1) break;
        WAITQ(B0,B1,B2,B3,B4,B5,B6,B7,B8,B9);   // deferred: hidden by the FMAs above
        wb += 64; c += 16;

        // ---- phase B: compute chunk c from B; prefetch chunk c+16 into A ----
        const bool pf2 = (ph + 2 < phases);
        if (pf2) {
            ISSUEN(A0,A1,A2,A3,A4,A5,A6,A7,A8,A9, wb);
            load_act((c + 16) << 2, a0, a1);
        }
        FMA_ALL(B0,B1,B2,B3,B4,B5,B6,B7,B8,B9, b0, b1);
        if (!pf2) break;
        WAITQ(A0,A1,A2,A3,A4,A5,A6,A7,A8,A9);
        wb += 64; c += 16;
    }

#pragma unroll
    for (int j = 0; j < NROW; j++)
        part[wv * PW + j * PJ + lane] = acc[j].x + acc[j].y;
    __syncthreads();

    // Epilogue: 640 (row,batch) items; out writes h-consecutive per 8 lanes.
    // part read addr%32 = (8w + 4j + b)%32 -> <=2-way, conflict-free.
    int j = -1, b = 0;
    if (tid < 512)      { b = tid >> 3;      j = tid & 7; }
    else if (tid < 640) { int u = tid - 512; b = u >> 1;  j = 8 + (u & 1); }
    if (j >= 0) {
        const int h = row_h(area, rb + j);
        float s = 0.f;
#pragma unroll
        for (int w16 = 0; w16 < 16; w16++) s += part[w16 * PW + j * PJ + b];
        const int r = r0 + j;
        float st = stateT[r * BB + b];
        float ns = st * (1.f - ALPHA_C) + ALPHA_C * (s + brec[h]);
        stateT[r * BB + b] = ns;
        float o = retanh_f(ns);
        out_t[(size_t)b * HH + h] = o;
        actOut[((h >> 1) << 7) + b * 2 + (h & 1)] = o;
    }
}

// ---- Fallback (no workspace): stream raw W, masked on the fly (R3-style).
__global__ __launch_bounds__(NTHR, 4) void step_raw(
    const float* __restrict__ W, const float* __restrict__ Win,
    const float* __restrict__ brec, const float* __restrict__ x_t,
    const float* __restrict__ actIn, float* __restrict__ actOut,
    float* __restrict__ stateT, float* __restrict__ out_t)
{
    __shared__ float part[16 * PW];
    const int tid = threadIdx.x, lane = tid & 63, wv = tid >> 6;
    const int area = blockIdx.x >> 6;
    const int rb = (blockIdx.x & 63) * NROW;
    int e_lo, n_e, i_lo, n_rec, n_tot;
    area_params(area, e_lo, n_e, i_lo, n_rec, n_tot);
    const int r0 = area * 640 + rb;
    const int C = n_tot >> 4;

    float2 acc[NROW];
#pragma unroll
    for (int j = 0; j < NROW; j++) acc[j] = make_float2(0.f, 0.f);

    for (int c = wv; c < C; c += 16) {
        const int p0 = c << 4;
        float2 av[8];
        int cbase;
        if (p0 < n_rec) {
            cbase = (p0 < n_e) ? (e_lo + p0) : (i_lo + (p0 - n_e));
            const float* ap = actIn + ((cbase >> 1) << 7) + lane * 2;
#pragma unroll
            for (int i = 0; i < 8; i++) av[i] = *(const float2*)(ap + (i << 7));
        } else {
            cbase = -1;
            const int k0 = p0 - n_rec;
            const float4* xp = (const float4*)(x_t + lane * INSZ + k0);
#pragma unroll
            for (int q = 0; q < 4; q++) {
                float4 v = xp[q];
                av[2 * q]     = make_float2(fmaxf(v.x, 0.f), fmaxf(v.y, 0.f));
                av[2 * q + 1] = make_float2(fmaxf(v.z, 0.f), fmaxf(v.w, 0.f));
            }
        }
#pragma unroll
        for (int j = 0; j < NROW; j++) {
            const int h = row_h(area, rb + j);
            const float sgn = (cbase >= 0 && p0 >= n_e) ? -1.f : 1.f;
            const float* wr = (cbase >= 0) ? (W + (size_t)h * HH + cbase)
                                           : (Win + (size_t)h * INSZ + (p0 - n_rec));
#pragma unroll
            for (int i = 0; i < 8; i++) {
                float wx = sgn * fabsf(wr[2 * i]);
                float wy = sgn * fabsf(wr[2 * i + 1]);
                acc[j].x = fmaf(wx, av[i].x, acc[j].x);
                acc[j].y = fmaf(wy, av[i].y, acc[j].y);
            }
        }
    }

#pragma unroll
    for (int j = 0; j < NROW; j++)
        part[wv * PW + j * PJ + lane] = acc[j].x + acc[j].y;
    __syncthreads();

    int j = -1, b = 0;
    if (tid < 512)      { b = tid >> 3;      j = tid & 7; }
    else if (tid < 640) { int u = tid - 512; b = u >> 1;  j = 8 + (u & 1); }
    if (j >= 0) {
        const int h = row_h(area, rb + j);
        float s = 0.f;
#pragma unroll
        for (int w16 = 0; w16 < 16; w16++) s += part[w16 * PW + j * PJ + b];
        {   // diag was included above; subtract it (mask has zero diag)
            float sgn = (h < ESZ) ? 1.f : -1.f;
            float ah = actIn[((h >> 1) << 7) + b * 2 + (h & 1)];
            s -= sgn * fabsf(W[(size_t)h * HH + h]) * ah;
        }
        const int r = r0 + j;
        float st = stateT[r * BB + b];
        float ns = st * (1.f - ALPHA_C) + ALPHA_C * (s + brec[h]);
        stateT[r * BB + b] = ns;
        float o = retanh_f(ns);
        out_t[(size_t)b * HH + h] = o;
        actOut[((h >> 1) << 7) + b * 2 + (h & 1)] = o;
    }
}

extern "C" void kernel_launch(void* const* d_in, const int* in_sizes, int n_in,
                              void* d_out, int out_size, void* d_ws, size_t ws_size,
                              hipStream_t stream) {
    const float* x      = (const float*)d_in[0];   // [TT][BB][INSZ]
    const float* W_in   = (const float*)d_in[1];   // [HH][INSZ]
    const float* W_rec  = (const float*)d_in[2];   // [HH][HH]
    const float* b_rec  = (const float*)d_in[3];   // [HH]
    const float* state0 = (const float*)d_in[4];   // [BB][HH]
    float* out = (float*)d_out;                    // [TT][BB][HH]
    float* ws = (float*)d_ws;

    const size_t packElems = (size_t)HH * PITCH;
    const size_t bufElems  = (size_t)HH * BB;
    const bool pre = ws_size >= (packElems + 3 * bufElems) * sizeof(float);

    float* Wp     = ws;
    float* stateT = pre ? (ws + packElems) : ws;
    float* actA   = stateT + bufElems;
    float* actB   = actA + bufElems;

    if (pre) pack_w<<<dim3(13, HH), 128, 0, stream>>>(W_rec, W_in, Wp);
    init_state2<<<(BB * HH) / 256, 256, 0, stream>>>(state0, stateT, actA);

    for (int t = 0; t < TT; t++) {
        const float* ai = (t & 1) ? actB : actA;
        float* ao       = (t & 1) ? actA : actB;
        const float* xt = x + (size_t)t * BB * INSZ;
        float* ot       = out + (size_t)t * BB * HH;
        if (pre)
            step5<<<NBLK, NTHR, 0, stream>>>(Wp, b_rec, xt, ai, ao, stateT, ot);
        else
            step_raw<<<NBLK, NTHR, 0, stream>>>(W_rec, W_in, b_rec, xt, ai, ao, stateT, ot);
    }
}